// Round 7
// baseline (12.109 us; speedup 1.0000x reference)
//
#include <hip/hip_runtime.h>

// LegendreActivation: out[b,o] = sum_w coeffs[o,w] * S[b,w]
// where S[b,w] = sum_i P_w(tanh(x[b,i]*scale)),  S[b,0] == 1024 exactly.
//
// R7 = R6 + packed-f32 phase 1: process element PAIRS as ext_vector_type(2)
// float so clang selects v_pk_fma_f32 / v_pk_mul_f32 / v_pk_add_f32
// (gfx90a+ packed f32 = the 2x behind the 157 TF spec vs 103 TF scalar).
// 14 VALU slots/elem -> 7 packed slots/elem; exp2/rcp stay scalar trans.

constexpr int I_DIM = 1024;
constexpr int O_DIM = 1024;
constexpr int NT    = 256;   // 4 waves
constexpr int G     = 4;     // rows per block, one wave per row

typedef float f32x4 __attribute__((ext_vector_type(4)));
typedef float f32x2 __attribute__((ext_vector_type(2)));

__global__ __launch_bounds__(NT, 4) void legendre_fused(
    const float* __restrict__ x,
    const float* __restrict__ coeffs,
    const float* __restrict__ scale_p,
    float* __restrict__ out)
{
    __shared__ float S_lds[G][8];   // per-row Legendre sums, w = 1..8

    const int t    = threadIdx.x;
    const int wave = t >> 6;        // 0..3 -> owns row b0+wave
    const int lane = t & 63;
    const int b0   = blockIdx.x * G;
    const int row  = b0 + wave;

    // ---- issue all global loads up front ----
    const float4* xr = reinterpret_cast<const float4*>(x + (size_t)row * I_DIM) + lane;
    float4 xv0 = xr[0];
    float4 xv1 = xr[64];
    float4 xv2 = xr[128];
    float4 xv3 = xr[192];

    const float4* ct4 = reinterpret_cast<const float4*>(coeffs) + (size_t)t * 9;
    float4 cv[9];
    #pragma unroll
    for (int k = 0; k < 9; ++k) cv[k] = ct4[k];

    float sc = fminf(fmaxf(scale_p[0], 0.1f), 2.0f);
    const float K = sc * 2.8853900817779268f;  // sc * 2*log2(e)
    const f32x2 K2    = {K, K};
    const f32x2 one2  = {1.f, 1.f};
    const f32x2 mtwo2 = {-2.f, -2.f};

    // ---- phase 1: packed power sums M_1..M_8 (8 pairs of elements) ----
    f32x2 m1 = {0.f, 0.f}, m2 = {0.f, 0.f}, m3 = {0.f, 0.f}, m4 = {0.f, 0.f},
          m5 = {0.f, 0.f}, m6 = {0.f, 0.f}, m7 = {0.f, 0.f}, m8 = {0.f, 0.f};

    const float vals[16] = {xv0.x, xv0.y, xv0.z, xv0.w,
                            xv1.x, xv1.y, xv1.z, xv1.w,
                            xv2.x, xv2.y, xv2.z, xv2.w,
                            xv3.x, xv3.y, xv3.z, xv3.w};
    #pragma unroll
    for (int e = 0; e < 8; ++e) {
        f32x2 v  = {vals[e], vals[e + 8]};
        f32x2 z  = v * K2;                            // pk_mul
        f32x2 ex;
        ex.x = __builtin_amdgcn_exp2f(z.x);           // trans (scalar)
        ex.y = __builtin_amdgcn_exp2f(z.y);
        f32x2 den = ex + one2;                        // pk_add
        f32x2 rc;
        rc.x = __builtin_amdgcn_rcpf(den.x);          // trans (scalar)
        rc.y = __builtin_amdgcn_rcpf(den.y);
        f32x2 xs = __builtin_elementwise_fma(mtwo2, rc, one2);  // pk_fma: tanh
        f32x2 p2 = xs * xs;                           // pk_mul
        f32x2 p3 = p2 * xs;                           // pk_mul
        f32x2 p4 = p2 * p2;                           // pk_mul
        m1 += xs;                                     // pk_add
        m2 += p2;                                     // pk_add
        m3 += p3;                                     // pk_add
        m4 += p4;                                     // pk_add
        m5 = __builtin_elementwise_fma(p2, p3, m5);   // pk_fma
        m6 = __builtin_elementwise_fma(p3, p3, m6);   // pk_fma
        m7 = __builtin_elementwise_fma(p3, p4, m7);   // pk_fma
        m8 = __builtin_elementwise_fma(p4, p4, m8);   // pk_fma
    }

    // horizontal add of the pair halves, then 64-lane butterfly
    float mm[8] = {m1.x + m1.y, m2.x + m2.y, m3.x + m3.y, m4.x + m4.y,
                   m5.x + m5.y, m6.x + m6.y, m7.x + m7.y, m8.x + m8.y};
    #pragma unroll
    for (int w = 0; w < 8; ++w) {
        #pragma unroll
        for (int msk = 32; msk >= 1; msk >>= 1)
            mm[w] += __shfl_xor(mm[w], msk, 64);
    }

    // monomial power sums -> Legendre sums (lane 0 writes)
    if (lane == 0) {
        const float M1 = mm[0], M2 = mm[1], M3 = mm[2], M4 = mm[3],
                    M5 = mm[4], M6 = mm[5], M7 = mm[6], M8 = mm[7];
        const float N = (float)I_DIM;   // M_0
        S_lds[wave][0] = M1;
        S_lds[wave][1] = 1.5f * M2 - 0.5f * N;
        S_lds[wave][2] = 2.5f * M3 - 1.5f * M1;
        S_lds[wave][3] = 4.375f * M4 - 3.75f * M2 + 0.375f * N;
        S_lds[wave][4] = 7.875f * M5 - 8.75f * M3 + 1.875f * M1;
        S_lds[wave][5] = 14.4375f * M6 - 19.6875f * M4 + 6.5625f * M2 - 0.3125f * N;
        S_lds[wave][6] = 26.8125f * M7 - 43.3125f * M5 + 19.6875f * M3 - 2.1875f * M1;
        S_lds[wave][7] = 50.2734375f * M8 - 93.84375f * M6 + 54.140625f * M4
                       - 9.84375f * M2 + 0.2734375f * N;
    }
    __syncthreads();

    // ---- phase 2: each thread writes out[b0+r][4t..4t+3] for r = 0..3 ----
    float c[36];
    #pragma unroll
    for (int k = 0; k < 9; ++k) {
        c[4 * k + 0] = cv[k].x; c[4 * k + 1] = cv[k].y;
        c[4 * k + 2] = cv[k].z; c[4 * k + 3] = cv[k].w;
    }

    #pragma unroll
    for (int r = 0; r < G; ++r) {
        float s0 = S_lds[r][0], s1 = S_lds[r][1], s2 = S_lds[r][2], s3 = S_lds[r][3];
        float s4 = S_lds[r][4], s5 = S_lds[r][5], s6 = S_lds[r][6], s7 = S_lds[r][7];

        f32x4 acc;
        #pragma unroll
        for (int ol = 0; ol < 4; ++ol) {
            float a = c[ol * 9 + 0] * (float)I_DIM;   // w=0: sum of ones
            a = fmaf(c[ol * 9 + 1], s0, a);
            a = fmaf(c[ol * 9 + 2], s1, a);
            a = fmaf(c[ol * 9 + 3], s2, a);
            a = fmaf(c[ol * 9 + 4], s3, a);
            a = fmaf(c[ol * 9 + 5], s4, a);
            a = fmaf(c[ol * 9 + 6], s5, a);
            a = fmaf(c[ol * 9 + 7], s6, a);
            a = fmaf(c[ol * 9 + 8], s7, a);
            acc[ol] = a;
        }
        // streaming store: don't pollute L2 (keeps x resident across replays)
        __builtin_nontemporal_store(acc,
            reinterpret_cast<f32x4*>(out + (size_t)(b0 + r) * O_DIM + 4 * t));
    }
}

extern "C" void kernel_launch(void* const* d_in, const int* in_sizes, int n_in,
                              void* d_out, int out_size, void* d_ws, size_t ws_size,
                              hipStream_t stream) {
    const float* x      = (const float*)d_in[0];
    const float* coeffs = (const float*)d_in[1];
    const float* scale  = (const float*)d_in[2];
    float* out          = (float*)d_out;

    const int B = in_sizes[0] / I_DIM;   // 4096
    const int nblocks = B / G;           // 1024

    legendre_fused<<<nblocks, NT, 0, stream>>>(x, coeffs, scale, out);
}